// Round 2
// baseline (352.175 us; speedup 1.0000x reference)
//
#include <hip/hip_runtime.h>
#include <hip/hip_bf16.h>
#include <math.h>

#define B_SZ 2
#define SEQ 4096
#define DMODEL 768
#define DSTATE 128
#define HEADDIM 64
#define DINNER 1536
#define NHEADS 24
#define DXBC 1792
#define DPROJ 3352
#define NPAD1 3584
#define CHUNK 128
#define NCHUNK 32
#define ROWS (B_SZ*SEQ)
#define LDTC 136   // padded LDS stride for conv input tile
#define LDE2 132   // padded LDS stride (fp32) for gemm2 epilogue tile
#define LDE3 264   // padded LDS stride (bf16) for gemm1 256-wide epilogue

typedef float floatx4 __attribute__((ext_vector_type(4)));
typedef __bf16 bf16x8 __attribute__((ext_vector_type(8)));

__device__ __forceinline__ float sigmoidf_(float x){ return 1.f/(1.f+expf(-x)); }
__device__ __forceinline__ float siluf_(float x){ return x/(1.f+expf(-x)); }
__device__ __forceinline__ float softplusf_(float x){ return (x>20.f)? x : log1pf(expf(x)); }
__device__ __forceinline__ __bf16 cvt_bf(float x){ __hip_bfloat16 t = __float2bfloat16(x); return *(__bf16*)&t; }

__device__ __forceinline__ void gload_lds16(const __hip_bfloat16* g, __hip_bfloat16* l){
    __builtin_amdgcn_global_load_lds(
        (const __attribute__((address_space(1))) void*)g,
        (__attribute__((address_space(3))) void*)l, 16, 0, 0);
}

// ======== GEMM1: 8-phase 256x256 template (m201 port) ========
// LDS = ring of 8 half-slots x 16 KiB. Per K-tile T (slots (T&1)*4 ..+3):
//   slot+0: W rows bn+0..127        slot+1: W rows bn+128..255
//   slot+2: A q0/q1 rows            slot+3: A q2/q3 rows
//   (A slot local row lr -> global row bm + ((lr>>5)&1)*128 + (hq*2+(lr>>6))*32 + (lr&31))
// Staging stream runs 7 halves ahead of the read stream; vmcnt(6) at tile
// boundaries only (vmcnt(0) entering the last tile).

template<int PART>
__device__ __forceinline__ void stage_half1(const __hip_bfloat16* __restrict__ Ag,
    const __hip_bfloat16* __restrict__ Wg, __hip_bfloat16* ring,
    int slot, int bm, int bn, int k0, int tid)
{
#pragma unroll
    for (int j = 0; j < 2; ++j) {
        int cc = j*512 + tid;
        int lr = cc >> 3, jc = cc & 7;
        int sj = jc ^ (lr & 7);
        int grow;
        const __hip_bfloat16* src;
        if constexpr (PART < 2) { grow = bn + PART*128 + lr; src = Wg; }
        else { grow = bm + ((lr>>5)&1)*128 + ((PART-2)*2 + (lr>>6))*32 + (lr&31); src = Ag; }
        gload_lds16(src + (size_t)grow*DMODEL + k0 + sj*8, ring + slot*8192 + cc*8);
    }
}

#define PHASE(Q, S0, STAGE, TAIL) { \
    const int lbA = ((Q)&1)*64 + wm2*32 + r16; \
    const int sA = (S0) + 2 + ((Q)>>1); \
    bf16x8 a00 = *(const bf16x8*)(ring + sA*8192 + lbA*64      + ck0*8); \
    bf16x8 a01 = *(const bf16x8*)(ring + sA*8192 + lbA*64      + ck1*8); \
    bf16x8 a10 = *(const bf16x8*)(ring + sA*8192 + (lbA+16)*64 + ck0*8); \
    bf16x8 a11 = *(const bf16x8*)(ring + sA*8192 + (lbA+16)*64 + ck1*8); \
    if ((Q) == 0) { \
        const int sB = (S0) + (wn4 >> 1); \
        const int lbB = (wn4 & 1)*64 + r16; \
        _Pragma("unroll") \
        for (int nf = 0; nf < 4; ++nf) { \
            bfr[nf][0] = *(const bf16x8*)(ring + sB*8192 + (lbB+nf*16)*64 + ck0*8); \
            bfr[nf][1] = *(const bf16x8*)(ring + sB*8192 + (lbB+nf*16)*64 + ck1*8); \
        } \
    } \
    STAGE; \
    __builtin_amdgcn_s_barrier(); \
    asm volatile("s_waitcnt lgkmcnt(0)" ::: "memory"); \
    __builtin_amdgcn_s_setprio(1); \
    _Pragma("unroll") \
    for (int n = 0; n < 4; ++n) acc[2*(Q)][n]   = __builtin_amdgcn_mfma_f32_16x16x32_bf16(a00, bfr[n][0], acc[2*(Q)][n],   0,0,0); \
    _Pragma("unroll") \
    for (int n = 0; n < 4; ++n) acc[2*(Q)][n]   = __builtin_amdgcn_mfma_f32_16x16x32_bf16(a01, bfr[n][1], acc[2*(Q)][n],   0,0,0); \
    _Pragma("unroll") \
    for (int n = 0; n < 4; ++n) acc[2*(Q)+1][n] = __builtin_amdgcn_mfma_f32_16x16x32_bf16(a10, bfr[n][0], acc[2*(Q)+1][n], 0,0,0); \
    _Pragma("unroll") \
    for (int n = 0; n < 4; ++n) acc[2*(Q)+1][n] = __builtin_amdgcn_mfma_f32_16x16x32_bf16(a11, bfr[n][1], acc[2*(Q)+1][n], 0,0,0); \
    __builtin_amdgcn_s_setprio(0); \
    TAIL; \
    __builtin_amdgcn_s_barrier(); \
}

__global__ __launch_bounds__(512, 2)
void gemm1_mfma(const __hip_bfloat16* __restrict__ A,   // fbf [ROWS][768]
                const __hip_bfloat16* __restrict__ W,   // wbf [3584][768]
                __hip_bfloat16* __restrict__ z16, __hip_bfloat16* __restrict__ xbc16,
                float* __restrict__ dtb, const float* __restrict__ dt_bias)
{
    __shared__ __align__(16) __hip_bfloat16 ring[8*8192];   // 128 KiB
    const int tid = threadIdx.x;
    const int lane = tid & 63, wave = tid >> 6;
    const int blk = blockIdx.x;
    const int m_tile = ((blk & 7) << 2) | ((blk >> 3) & 3);   // 32 M-tiles, XCD band
    const int bx = blk >> 5;                                   // N-tile 0..13
    const int bm = m_tile*256, bn = bx*256;
    const int wm2 = wave & 1, wn4 = wave >> 1;
    const int r16 = lane & 15, qbase = lane >> 4, sw = r16 & 7;
    const int ck0 = qbase ^ sw, ck1 = (qbase + 4) ^ sw;
    floatx4 acc[8][4] = {};
    bf16x8 bfr[4][2];
    // prologue: stage halves h0..h6 (tile0 complete + 3 halves of tile1)
    stage_half1<0>(A,W,ring, 0, bm,bn, 0,  tid);
    stage_half1<1>(A,W,ring, 1, bm,bn, 0,  tid);
    stage_half1<2>(A,W,ring, 2, bm,bn, 0,  tid);
    stage_half1<3>(A,W,ring, 3, bm,bn, 0,  tid);
    stage_half1<0>(A,W,ring, 4, bm,bn, 64, tid);
    stage_half1<1>(A,W,ring, 5, bm,bn, 64, tid);
    stage_half1<2>(A,W,ring, 6, bm,bn, 64, tid);
    asm volatile("s_waitcnt vmcnt(6)" ::: "memory");   // tile0 landed
    __builtin_amdgcn_s_barrier();
    // main loop: 12 K-tiles, 2 per iteration, peel last pair
#pragma unroll 1
    for (int i = 0; i < 5; ++i) {
        const int kA = (2*i+1)*64, kB = (2*i+2)*64, kC = (2*i+3)*64;
        PHASE(0, 0, stage_half1<3>(A,W,ring,7,bm,bn,kA,tid), (void)0);
        PHASE(1, 0, stage_half1<0>(A,W,ring,0,bm,bn,kB,tid), (void)0);
        PHASE(2, 0, stage_half1<1>(A,W,ring,1,bm,bn,kB,tid), (void)0);
        PHASE(3, 0, stage_half1<2>(A,W,ring,2,bm,bn,kB,tid),
              asm volatile("s_waitcnt vmcnt(6)" ::: "memory"));
        PHASE(0, 4, stage_half1<3>(A,W,ring,3,bm,bn,kB,tid), (void)0);
        PHASE(1, 4, stage_half1<0>(A,W,ring,4,bm,bn,kC,tid), (void)0);
        PHASE(2, 4, stage_half1<1>(A,W,ring,5,bm,bn,kC,tid), (void)0);
        PHASE(3, 4, stage_half1<2>(A,W,ring,6,bm,bn,kC,tid),
              asm volatile("s_waitcnt vmcnt(6)" ::: "memory"));
    }
    // peeled tiles 10, 11
    PHASE(0, 0, stage_half1<3>(A,W,ring,7,bm,bn,11*64,tid), (void)0);
    PHASE(1, 0, (void)0, (void)0);
    PHASE(2, 0, (void)0, (void)0);
    PHASE(3, 0, (void)0, asm volatile("s_waitcnt vmcnt(0)" ::: "memory"));
    PHASE(0, 4, (void)0, (void)0);
    PHASE(1, 4, (void)0, (void)0);
    PHASE(2, 4, (void)0, (void)0);
    PHASE(3, 4, (void)0, (void)0);

    const int col = lane & 15, rowq = (lane >> 4)*4;
    if (bx == 13) {                       // dt tile: cols 3328..3351
        if (wn4 == 0) {
#pragma unroll
            for (int m = 0; m < 8; ++m)
#pragma unroll
                for (int n = 0; n < 2; ++n) {
                    int h = n*16 + col;
                    if (h < NHEADS)
#pragma unroll
                        for (int r = 0; r < 4; ++r) {
                            int mrow = bm + wm2*128 + m*16 + rowq + r;
                            dtb[(size_t)mrow*NHEADS + h] =
                                softplusf_(acc[m][n][r] + dt_bias[h]);
                        }
                }
        }
        return;
    }
    __hip_bfloat16* Tsm = ring;           // [128][LDE3]
    __hip_bfloat16* dst; int ldd;
    if (bx < 6) { dst = z16 + bx*256;            ldd = DINNER; }
    else        { dst = xbc16 + bx*256 - DINNER; ldd = DXBC;  }
    for (int half = 0; half < 2; ++half) {
        if (wm2 == half) {
#pragma unroll
            for (int m = 0; m < 8; ++m)
#pragma unroll
                for (int n = 0; n < 4; ++n)
#pragma unroll
                    for (int r = 0; r < 4; ++r)
                        Tsm[(m*16 + rowq + r)*LDE3 + wn4*64 + n*16 + col] =
                            __float2bfloat16(acc[m][n][r]);
        }
        __syncthreads();
#pragma unroll
        for (int it = 0; it < 8; ++it) {
            int e = it*512 + tid;
            int row = e >> 5, c0 = (e & 31)*8;
            bf16x8 v = *(const bf16x8*)(Tsm + row*LDE3 + c0);
            *(bf16x8*)(dst + (size_t)(bm + half*128 + row)*ldd + c0) = v;
        }
        __syncthreads();
    }
}

// ======== GEMM2 (round-0 proven structure): 256x128 tile, 48 KiB, 3 blk/CU ====
__global__ __launch_bounds__(512)
void gemm2_mfma(const __hip_bfloat16* __restrict__ A,   // y16 [ROWS][1536] (gated)
                const __hip_bfloat16* __restrict__ W,   // owbf [768][1536]
                float* __restrict__ C,
                const float* __restrict__ gate, const float* __restrict__ resid,
                const float* __restrict__ rowsq)
{
    __shared__ __align__(16) char smem[49152];
    __shared__ float scale_lds[256];
    __hip_bfloat16* Asm = (__hip_bfloat16*)smem;        // [256][64]
    __hip_bfloat16* Wsm = Asm + 256*64;                 // [128][64]
    const int tid = threadIdx.x;
    const int lane = tid & 63, wave = tid >> 6;
    const int blk = blockIdx.x;
    const int m_tile = ((blk & 7) << 2) | ((blk >> 3) & 3);
    const int bm = m_tile*256, bn = (blk >> 5)*128;     // n-tile 0..5
    const int wm = (wave & 3)*64, wn = (wave >> 2)*64;
    const int r16 = lane & 15, qbase = lane >> 4, sw = r16 & 7;
    floatx4 acc[4][4] = {};
    for (int k0 = 0; k0 < DINNER; k0 += 64) {
#pragma unroll
        for (int j = 0; j < 4; ++j) {
            int cc = j*512 + tid;
            int row = cc >> 3, jc = cc & 7;
            int sj = jc ^ (row & 7);
            gload_lds16(A + (size_t)(bm+row)*DINNER + k0 + sj*8, Asm + cc*8);
        }
#pragma unroll
        for (int j = 0; j < 2; ++j) {
            int cc = j*512 + tid;
            int row = cc >> 3, jc = cc & 7;
            int sj = jc ^ (row & 7);
            gload_lds16(W + (size_t)(bn+row)*DINNER + k0 + sj*8, Wsm + cc*8);
        }
        __syncthreads();
#pragma unroll
        for (int ks = 0; ks < 2; ++ks) {
            const int kq = ((qbase + ks*4) ^ sw)*8;
            bf16x8 af[4], wf[4];
#pragma unroll
            for (int i = 0; i < 4; ++i) {
                af[i] = *(const bf16x8*)(Asm + (wm + i*16 + r16)*64 + kq);
                wf[i] = *(const bf16x8*)(Wsm + (wn + i*16 + r16)*64 + kq);
            }
#pragma unroll
            for (int mi = 0; mi < 4; ++mi)
#pragma unroll
                for (int ni = 0; ni < 4; ++ni)
                    acc[mi][ni] = __builtin_amdgcn_mfma_f32_16x16x32_bf16(
                        af[mi], wf[ni], acc[mi][ni], 0, 0, 0);
        }
        __syncthreads();
    }
    if (tid < 256)
        scale_lds[tid] = rsqrtf(rowsq[bm + tid] * (1.f/DINNER) + 1e-5f);
    float gs = sigmoidf_(gate[0]);
    __syncthreads();
    const int col = lane & 15, rowq = (lane >> 4)*4;
    float* Tsm = (float*)smem;   // 64 x LDE2 fp32
    for (int qp = 0; qp < 4; ++qp) {
        if ((wave & 3) == qp) {
#pragma unroll
            for (int mi = 0; mi < 4; ++mi)
#pragma unroll
                for (int ni = 0; ni < 4; ++ni)
#pragma unroll
                    for (int r = 0; r < 4; ++r)
                        Tsm[(mi*16 + rowq + r)*LDE2 + wn + ni*16 + col] = acc[mi][ni][r];
        }
        __syncthreads();
#pragma unroll
        for (int it = 0; it < 4; ++it) {
            int e = it*512 + tid;
            int row = e >> 5, c0 = (e & 31)*4;
            float4 v = *(const float4*)(Tsm + row*LDE2 + c0);
            float sc = gs * scale_lds[qp*64 + row];
            size_t off = (size_t)(bm + qp*64 + row)*DMODEL + bn + c0;
            float4 rv = *(const float4*)(resid + off);
            v.x = sc*v.x + rv.x; v.y = sc*v.y + rv.y;
            v.z = sc*v.z + rv.z; v.w = sc*v.w + rv.w;
            *(float4*)(C + off) = v;
        }
        __syncthreads();
    }
}

// ---------------- fused fp32 -> bf16 casts, vectorized 8 elem/thread ----------------
#define NC1 (ROWS*DMODEL)
#define NC2 (NPAD1*DMODEL)
#define NC3 (DMODEL*DINNER)
#define NV1 (NC1/8)
#define NV2 (NC2/8)
#define NV3 (NC3/8)
__global__ __launch_bounds__(256)
void cast_all(const float* __restrict__ feature, const float* __restrict__ in_w,
              const float* __restrict__ out_w, const float* __restrict__ nw,
              __hip_bfloat16* __restrict__ fbf, __hip_bfloat16* __restrict__ wbf,
              __hip_bfloat16* __restrict__ owbf)
{
    int v = blockIdx.x*256 + threadIdx.x;
    if (v < NV1) {
        int i = v*8;
        float4 a = *(const float4*)(feature + i);
        float4 b = *(const float4*)(feature + i + 4);
        bf16x8 o;
        o[0]=cvt_bf(a.x); o[1]=cvt_bf(a.y); o[2]=cvt_bf(a.z); o[3]=cvt_bf(a.w);
        o[4]=cvt_bf(b.x); o[5]=cvt_bf(b.y); o[6]=cvt_bf(b.z); o[7]=cvt_bf(b.w);
        *(bf16x8*)(fbf + i) = o;
    } else if (v < NV1 + NV2) {
        int j = (v - NV1)*8;
        int n = j / DMODEL, k = j - n*DMODEL;
        bf16x8 o;
        if (n < DPROJ) {
            const float* s = in_w + (size_t)n*DMODEL + k;
            float4 a = *(const float4*)(s);
            float4 b = *(const float4*)(s + 4);
            o[0]=cvt_bf(a.x); o[1]=cvt_bf(a.y); o[2]=cvt_bf(a.z); o[3]=cvt_bf(a.w);
            o[4]=cvt_bf(b.x); o[5]=cvt_bf(b.y); o[6]=cvt_bf(b.z); o[7]=cvt_bf(b.w);
        } else {
#pragma unroll
            for (int q = 0; q < 8; ++q) o[q] = (__bf16)0.f;
        }
        *(bf16x8*)(wbf + j) = o;
    } else if (v < NV1 + NV2 + NV3) {
        int j = (v - NV1 - NV2)*8;
        int k = j % DINNER;
        float4 a  = *(const float4*)(out_w + j);
        float4 b  = *(const float4*)(out_w + j + 4);
        float4 na = *(const float4*)(nw + k);
        float4 nb = *(const float4*)(nw + k + 4);
        bf16x8 o;
        o[0]=cvt_bf(a.x*na.x); o[1]=cvt_bf(a.y*na.y); o[2]=cvt_bf(a.z*na.z); o[3]=cvt_bf(a.w*na.w);
        o[4]=cvt_bf(b.x*nb.x); o[5]=cvt_bf(b.y*nb.y); o[6]=cvt_bf(b.z*nb.z); o[7]=cvt_bf(b.w*nb.w);
        *(bf16x8*)(owbf + j) = o;
    }
}

// ======== conv4+SiLU, emits x_t/B_n/B_t/C_n in MFMA-ready layouts ========
__global__ __launch_bounds__(256)
void conv_k(const __hip_bfloat16* __restrict__ xbc16, const float* __restrict__ cw,
            const float* __restrict__ cbias,
            __hip_bfloat16* __restrict__ x_t,
            __hip_bfloat16* __restrict__ B_n, __hip_bfloat16* __restrict__ B_t,
            __hip_bfloat16* __restrict__ C_n)
{
    __shared__ __align__(16) __hip_bfloat16 in[131*LDTC];
    int ct = blockIdx.x, lt = blockIdx.y, b = blockIdx.z;
    int tid = threadIdx.x;
    int base = lt*128;
    for (int it = 0; it < 2096; it += 256) {
        int e = it + tid; if (e >= 2096) break;
        int row = e >> 4, c0 = (e & 15)*8;
        int l = base - 3 + row;
        bf16x8 v;
        if (l < 0) { for (int j = 0; j < 8; ++j) v[j] = (__bf16)0.f; }
        else v = *(const bf16x8*)(xbc16 + ((size_t)b*SEQ + l)*DXBC + ct*128 + c0);
        *(bf16x8*)(in + row*LDTC + c0) = v;
    }
    __syncthreads();
    int ch = tid & 127, lh = tid >> 7, l0 = lh*64;
    int g = ct*128 + ch;
    float w0 = cw[g*4+0], w1 = cw[g*4+1], w2 = cw[g*4+2], w3 = cw[g*4+3];
    float bias = cbias[g];
    float a0 = __bfloat162float(in[(l0+0)*LDTC + ch]);
    float a1 = __bfloat162float(in[(l0+1)*LDTC + ch]);
    float a2 = __bfloat162float(in[(l0+2)*LDTC + ch]);
    size_t trow = 0;
    if (ct < 12)      trow = ((size_t)b*NHEADS + (g>>6))*HEADDIM + (g & 63);
    else if (ct == 12) trow = (size_t)b*DSTATE + ch;
    bf16x8 obuf;
#pragma unroll
    for (int li = 0; li < 64; ++li) {
        float a3 = __bfloat162float(in[(l0+li+3)*LDTC + ch]);
        float o = siluf_(bias + w0*a0 + w1*a1 + w2*a2 + w3*a3);
        a0 = a1; a1 = a2; a2 = a3;
        __hip_bfloat16 ob = __float2bfloat16(o);
        size_t rr = (size_t)b*SEQ + base + l0 + li;
        if (ct == 12)      B_n[rr*DSTATE + ch] = ob;
        else if (ct == 13) C_n[rr*DSTATE + ch] = ob;
        obuf[li & 7] = *(const __bf16*)&ob;
        if ((li & 7) == 7 && ct <= 12) {
            __hip_bfloat16* dst = (ct < 12) ? x_t : B_t;
            *(bf16x8*)(dst + trow*SEQ + base + l0 + (li - 7)) = obuf;
        }
    }
}

// ---------------- intra-chunk inclusive cumsum of dt*A ----------------
__global__ __launch_bounds__(128)
void scan_k(const float* __restrict__ dtb, const float* __restrict__ A_log,
            float* __restrict__ acum)
{
    int c = blockIdx.x & 31;
    int h = (blockIdx.x >> 5) % NHEADS;
    int b = blockIdx.x / (32*NHEADS);
    int l = threadIdx.x;
    float A = -expf(A_log[h]);
    size_t row = (size_t)b*SEQ + c*CHUNK + l;
    float v = dtb[row*NHEADS + h] * A;
    __shared__ float sh[128];
    sh[l] = v; __syncthreads();
    for (int off=1; off<128; off<<=1){
        float t = (l>=off) ? sh[l-off] : 0.f;
        __syncthreads();
        sh[l] += t;
        __syncthreads();
    }
    acum[((b*NHEADS+h)*NCHUNK + c)*CHUNK + l] = sh[l];
}

// ======== CB[l][s] = sum_n C[l][n]*B[s][n], per (b,c), LDS-free, tril tiles only ========
__global__ __launch_bounds__(256)
void cb_mfma(const __hip_bfloat16* __restrict__ B_n, const __hip_bfloat16* __restrict__ C_n,
             __hip_bfloat16* __restrict__ CB16)
{
    int c = blockIdx.x & 31, b = blockIdx.x >> 5;
    size_t base = (size_t)b*SEQ + c*CHUNK;
    int tid = threadIdx.x, lane = tid & 63, wave = tid >> 6;
    int r16 = lane & 15, kq = (lane>>4)*8;
    floatx4 acc[2][8] = {};
#pragma unroll
    for (int ks = 0; ks < 4; ++ks) {
        int k0 = ks*32 + kq;
        bf16x8 af[2], bfv[8];
#pragma unroll
        for (int mt = 0; mt < 2; ++mt)
            af[mt] = *(const bf16x8*)(C_n + (base + (wave*2+mt)*16 + r16)*DSTATE + k0);
#pragma unroll
        for (int st = 0; st < 8; ++st)
            bfv[st] = *(const bf16x8*)(B_n + (base + st*16 + r16)*DSTATE + k0);
#pragma unroll
        for (int mt = 0; mt < 2; ++mt)
#pragma unroll
            for (int st = 0; st < 8; ++st)
                if (st <= wave*2+mt)
                    acc[mt][st] = __builtin_amdgcn_mfma_f32_16x16x32_bf16(
                        af[mt], bfv[st], acc[mt][st], 0,0,0);
    }
    size_t cbb = (size_t)(b*NCHUNK+c)*CHUNK*CHUNK;
    int scol = lane & 15, rowq = (lane>>4)*4;
#pragma unroll
    for (int mt = 0; mt < 2; ++mt)
#pragma unroll
        for (int st = 0; st < 8; ++st)
            if (st <= wave*2+mt)
#pragma unroll
                for (int r = 0; r < 4; ++r)
                    CB16[cbb + (size_t)((wave*2+mt)*16 + rowq + r)*CHUNK + st*16 + scol] =
                        __float2bfloat16(acc[mt][st][r]);
}

// ======== states[p][n] = sum_l (x[l,p]*f[l]) * B[l,n], f = dt*dec ========
__global__ __launch_bounds__(256)
void states_mfma(const __hip_bfloat16* __restrict__ x_t, const __hip_bfloat16* __restrict__ B_t,
                 const float* __restrict__ dtb, const float* __restrict__ acum,
                 __hip_bfloat16* __restrict__ states)
{
    __shared__ float f[128];
    int c = blockIdx.x & 31;
    int h = (blockIdx.x>>5) % NHEADS;
    int b = blockIdx.x/(32*NHEADS);
    int tid = threadIdx.x, lane = tid & 63, wave = tid >> 6;
    int arow = ((b*NHEADS+h)*NCHUNK + c)*CHUNK;
    size_t rbase = (size_t)b*SEQ + c*CHUNK;
    if (tid < 128) {
        float alast = acum[arow + 127];
        f[tid] = dtb[(rbase + tid)*NHEADS + h] * expf(alast - acum[arow + tid]);
    }
    __syncthreads();
    int r16 = lane & 15, kq = (lane>>4)*8;
    size_t xtb = ((size_t)b*NHEADS + h)*HEADDIM;
    int cl = c*CHUNK;
    floatx4 acc[8] = {};
#pragma unroll
    for (int ks = 0; ks < 4; ++ks) {
        int k0 = ks*32 + kq;
        bf16x8 xa = *(const bf16x8*)(x_t + (xtb + wave*16 + r16)*SEQ + cl + k0);
        bf16x8 af;
#pragma unroll
        for (int j = 0; j < 8; ++j)
            af[j] = (__bf16)((float)xa[j] * f[k0 + j]);
        bf16x8 bfv[8];
#pragma unroll
        for (int nt = 0; nt < 8; ++nt)
            bfv[nt] = *(const bf16x8*)(B_t + ((size_t)b*DSTATE + nt*16 + r16)*SEQ + cl + k0);
#pragma unroll
        for (int nt = 0; nt < 8; ++nt)
            acc[nt] = __builtin_amdgcn_mfma_f32_16x16x32_bf16(af, bfv[nt], acc[nt], 0,0,0);
    }
    size_t sb = ((size_t)(b*NCHUNK+c)*NHEADS + h)*(HEADDIM*DSTATE);
    int ncol = lane & 15, rowq = (lane>>4)*4;
#pragma unroll
    for (int nt = 0; nt < 8; ++nt)
#pragma unroll
        for (int r = 0; r < 4; ++r)
            states[sb + (size_t)(wave*16 + rowq + r)*DSTATE + nt*16 + ncol] =
                __float2bfloat16(acc[nt][r]);
}

// ---- sequential inter-chunk recurrence, in place (bf16): states[c] := prev[c] ----
__global__ __launch_bounds__(256)
void recur_k(__hip_bfloat16* __restrict__ states, const float* __restrict__ acum)
{
    int pb = blockIdx.x & 3;
    int bh = blockIdx.x >> 2;
    int h = bh % NHEADS, b = bh / NHEADS;
    int voff = (pb*256 + threadIdx.x)*8;
    const size_t cstride = (size_t)NHEADS*HEADDIM*DSTATE;
    size_t base0 = ((size_t)(b*NCHUNK)*NHEADS + h)*(HEADDIM*DSTATE) + voff;
    bf16x8 st[NCHUNK];
    float ev[NCHUNK];
#pragma unroll
    for (int c = 0; c < NCHUNK; ++c)
        st[c] = *(const bf16x8*)(states + base0 + (size_t)c*cstride);
#pragma unroll
    for (int c = 0; c < NCHUNK; ++c)
        ev[c] = expf(acum[((b*NHEADS+h)*NCHUNK + c)*CHUNK + 127]);
    float S[8] = {};
#pragma unroll
    for (int c = 0; c < NCHUNK; ++c) {
        bf16x8 pv;
#pragma unroll
        for (int j = 0; j < 8; ++j) {
            pv[j] = (__bf16)S[j];
            S[j] = S[j]*ev[c] + (float)st[c][j];
        }
        *(bf16x8*)(states + base0 + (size_t)c*cstride) = pv;
    }
}

// ======== Y = [tril(CB*exp(dAc)*dt)+D*I] @ x + (C*exp(ac)) @ prev^T; then
//          g = Y*silu(z) -> y16; rowsq += per-row sum(g^2) (atomic) ========
__global__ __launch_bounds__(512)
void y_mfma(const __hip_bfloat16* __restrict__ x_t, const __hip_bfloat16* __restrict__ z16,
            const __hip_bfloat16* __restrict__ C_n, const __hip_bfloat16* __restrict__ CB16,
            const __hip_bfloat16* __restrict__ states, const float* __restrict__ dtb,
            const float* __restrict__ acum, const float* __restrict__ Dp,
            __hip_bfloat16* __restrict__ y16, float* __restrict__ rowsq)
{
    __shared__ float ac[128], dts[128];
    int c = blockIdx.x & 31;
    int h = (blockIdx.x>>5) % NHEADS;
    int b = blockIdx.x/(32*NHEADS);
    int tid = threadIdx.x, lane = tid & 63, wave = tid >> 6;
    int arow = ((b*NHEADS+h)*NCHUNK + c)*CHUNK;
    size_t rbase = (size_t)b*SEQ + c*CHUNK;
    if (tid < 128) {
        ac[tid]  = acum[arow + tid];
        dts[tid] = dtb[(rbase + tid)*NHEADS + h];
    }
    __syncthreads();
    int r16 = lane & 15, kq = (lane>>4)*8;
    int l = wave*16 + r16;
    float acl = ac[l];
    float Dh = Dp[h];
    size_t cbb = (size_t)(b*NCHUNK+c)*CHUNK*CHUNK;
    size_t xtb = ((size_t)b*NHEADS + h)*HEADDIM;
    int cl = c*CHUNK;
    floatx4 acc[4] = {};
    int nks = ((wave+1)*16 + 31) >> 5;
    for (int ks = 0; ks < nks; ++ks) {
        int k0 = ks*32 + kq;
        bf16x8 cbv = *(const bf16x8*)(CB16 + cbb + (size_t)l*CHUNK + k0);
        bf16x8 af;
#pragma unroll
        for (int j = 0; j < 8; ++j) {
            int s = k0 + j;
            float w = (s <= l) ? (float)cbv[j] * expf(acl - ac[s]) * dts[s] : 0.f;
            if (s == l) w += Dh;               // D*x folded into the diagonal
            af[j] = (__bf16)w;
        }
        bf16x8 bfv[4];
#pragma unroll
        for (int pt = 0; pt < 4; ++pt)
            bfv[pt] = *(const bf16x8*)(x_t + (xtb + pt*16 + r16)*SEQ + cl + k0);
#pragma unroll
        for (int pt = 0; pt < 4; ++pt)
            acc[pt] = __builtin_amdgcn_mfma_f32_16x16x32_bf16(af, bfv[pt], acc[pt], 0,0,0);
    }
    float eal = expf(acl);
    size_t sb = ((size_t)(b*NCHUNK+c)*NHEADS + h)*(HEADDIM*DSTATE);
#pragma unroll
    for (int ks = 0; ks < 4; ++ks) {
        int k0 = ks*32 + kq;
        bf16x8 cv = *(const bf16x8*)(C_n + (rbase + l)*DSTATE + k0);
        bf16x8 af;
#pragma unroll
        for (int j = 0; j < 8; ++j)
            af[j] = (__bf16)((float)cv[j] * eal);
        bf16x8 bfv[4];
#pragma unroll
        for (int pt = 0; pt < 4; ++pt)
            bfv[pt] = *(const bf16x8*)(states + sb + (size_t)(pt*16 + r16)*DSTATE + k0);
#pragma unroll
        for (int pt = 0; pt < 4; ++pt)
            acc[pt] = __builtin_amdgcn_mfma_f32_16x16x32_bf16(af, bfv[pt], acc[pt], 0,0,0);
    }
    // epilogue: g = acc * silu(z); store; per-row sumsq via shuffle + atomic
    int pcol = lane & 15, rowq = (lane>>4)*4;
    float sr[4] = {0.f, 0.f, 0.f, 0.f};
#pragma unroll
    for (int pt = 0; pt < 4; ++pt)
#pragma unroll
        for (int r = 0; r < 4; ++r) {
            int ll = wave*16 + rowq + r;
            int p = pt*16 + pcol;
            size_t rr = rbase + ll;
            float zv = __bfloat162float(z16[rr*DINNER + h*HEADDIM + p]);
            float g = acc[pt][r] * siluf_(zv);
            y16[rr*DINNER + h*HEADDIM + p] = __float2bfloat16(g);
            sr[r] += g*g;
        }
#pragma unroll
    for (int r = 0; r < 4; ++r) {
        float s = sr[r];
        s += __shfl_xor(s, 1); s += __shfl_xor(s, 2);
        s += __shfl_xor(s, 4); s += __shfl_xor(s, 8);
        if (pcol == 0)
            atomicAdd(rowsq + rbase + wave*16 + rowq + r, s);
    }
}

extern "C" void kernel_launch(void* const* d_in, const int* in_sizes, int n_in,
                              void* d_out, int out_size, void* d_ws, size_t ws_size,
                              hipStream_t stream)
{
    const float* feature = (const float*)d_in[0];
    const float* gate1   = (const float*)d_in[1];
    const float* in_w    = (const float*)d_in[2];
    const float* conv_w  = (const float*)d_in[3];
    const float* conv_b  = (const float*)d_in[4];
    const float* dt_bias = (const float*)d_in[5];
    const float* A_log   = (const float*)d_in[6];
    const float* Dp      = (const float*)d_in[7];
    const float* norm_w  = (const float*)d_in[8];
    const float* out_w   = (const float*)d_in[9];
    float* out = (float*)d_out;

    // workspace layout — ~161 MB (< 256 MiB)
    char* p = (char*)d_ws;
    __hip_bfloat16* z16   = (__hip_bfloat16*)p; p += (size_t)ROWS*DINNER*2;  // 25.2 MB
    __hip_bfloat16* xbc16 = (__hip_bfloat16*)p; p += (size_t)ROWS*DXBC*2;    // 29.4 MB
    __hip_bfloat16* x_t   = (__hip_bfloat16*)p; p += (size_t)ROWS*DINNER*2;  // 25.2 MB
    __hip_bfloat16* B_n   = (__hip_bfloat16*)p; p += (size_t)ROWS*DSTATE*2;  // 2.1 MB
    __hip_bfloat16* B_t   = (__hip_bfloat16*)p; p += (size_t)ROWS*DSTATE*2;  // 2.1 MB
    __hip_bfloat16* C_n   = (__hip_bfloat16*)p; p += (size_t)ROWS*DSTATE*2;  // 2.1 MB
    float* dtb    = (float*)p;            p += (size_t)ROWS*NHEADS*4;        // 0.8 MB
    float* acum   = (float*)p;            p += (size_t)B_SZ*NHEADS*NCHUNK*CHUNK*4; // 0.8 MB
    float* rowsq  = (float*)p;            p += (size_t)ROWS*4;               // 32 KB
    __hip_bfloat16* CB16 = (__hip_bfloat16*)p; p += (size_t)B_SZ*NCHUNK*CHUNK*CHUNK*2; // 2.1 MB
    __hip_bfloat16* states = (__hip_bfloat16*)p; p += (size_t)B_SZ*NCHUNK*NHEADS*HEADDIM*DSTATE*2; // 25.2 MB
    __hip_bfloat16* y16  = (__hip_bfloat16*)p; p += (size_t)ROWS*DINNER*2;   // 25.2 MB
    __hip_bfloat16* fbf  = (__hip_bfloat16*)p; p += (size_t)ROWS*DMODEL*2;   // 12.6 MB
    __hip_bfloat16* wbf  = (__hip_bfloat16*)p; p += (size_t)NPAD1*DMODEL*2;  //  5.5 MB
    __hip_bfloat16* owbf = (__hip_bfloat16*)p; p += (size_t)DMODEL*DINNER*2; //  2.4 MB

    cast_all<<<(NV1+NV2+NV3+255)/256, 256, 0, stream>>>(feature, in_w, out_w, norm_w,
                                                        fbf, wbf, owbf);
    hipMemsetAsync(rowsq, 0, (size_t)ROWS*4, stream);

    gemm1_mfma<<<14*32, 512, 0, stream>>>(fbf, wbf, z16, xbc16, dtb, dt_bias);
    conv_k<<<dim3(14, 32, B_SZ), 256, 0, stream>>>(xbc16, conv_w, conv_b,
                                                   x_t, B_n, B_t, C_n);
    scan_k<<<B_SZ*NHEADS*NCHUNK, 128, 0, stream>>>(dtb, A_log, acum);
    cb_mfma<<<B_SZ*NCHUNK, 256, 0, stream>>>(B_n, C_n, CB16);
    states_mfma<<<B_SZ*NHEADS*NCHUNK, 256, 0, stream>>>(x_t, B_t, dtb, acum, states);
    recur_k<<<B_SZ*NHEADS*4, 256, 0, stream>>>(states, acum);
    y_mfma<<<B_SZ*NHEADS*NCHUNK, 512, 0, stream>>>(x_t, z16, C_n, CB16, states,
                                                   dtb, acum, Dp, y16, rowsq);
    gemm2_mfma<<<6*32, 512, 0, stream>>>(y16, owbf, out, gate1, feature, rowsq);
}

// Round 3
// 337.517 us; speedup vs baseline: 1.0434x; 1.0434x over previous
//
#include <hip/hip_runtime.h>
#include <hip/hip_bf16.h>
#include <math.h>

#define B_SZ 2
#define SEQ 4096
#define DMODEL 768
#define DSTATE 128
#define HEADDIM 64
#define DINNER 1536
#define NHEADS 24
#define DXBC 1792
#define DPROJ 3352
#define NPAD1 3456
#define CHUNK 128
#define NCHUNK 32
#define ROWS (B_SZ*SEQ)
#define LDTC 136   // padded LDS stride for conv input tile
#define LDE 136    // padded LDS stride (bf16) for gemm1 epilogue tile
#define LDE2 132   // padded LDS stride (fp32) for gemm2 epilogue tile

typedef float floatx4 __attribute__((ext_vector_type(4)));
typedef __bf16 bf16x8 __attribute__((ext_vector_type(8)));

__device__ __forceinline__ float sigmoidf_(float x){ return 1.f/(1.f+expf(-x)); }
__device__ __forceinline__ float siluf_(float x){ return x/(1.f+expf(-x)); }
__device__ __forceinline__ float softplusf_(float x){ return (x>20.f)? x : log1pf(expf(x)); }
__device__ __forceinline__ __bf16 cvt_bf(float x){ __hip_bfloat16 t = __float2bfloat16(x); return *(__bf16*)&t; }

__device__ __forceinline__ void gload_lds16(const __hip_bfloat16* g, __hip_bfloat16* l){
    __builtin_amdgcn_global_load_lds(
        (const __attribute__((address_space(1))) void*)g,
        (__attribute__((address_space(3))) void*)l, 16, 0, 0);
}

// ---- shared GEMM machinery: 256x128 tile, BK=32, double-buffered (48 KiB total),
// one barrier per K-step; stage(t+1) issued BEFORE compute(t) so the
// global_load_lds latency hides under ds_read+MFMA (catalog minimum 2-phase). ----

// 32-wide rows: 4 chunks of 16B per row; swizzle j ^ ((row ^ row>>2) & 3)
// gives exact 2-way bank aliasing on ds_read_b128 (free on wave64).
template<int LDK>
__device__ __forceinline__ void stage32(const __hip_bfloat16* __restrict__ A,
    const __hip_bfloat16* __restrict__ W,
    __hip_bfloat16* SA, __hip_bfloat16* SW, int bm, int bn, int k0, int tid)
{
#pragma unroll
    for (int j = 0; j < 2; ++j) {
        int cc = j*512 + tid;                 // A: 1024 chunks (256 rows x 4)
        int row = cc >> 2, jc = cc & 3;
        int sj = jc ^ ((row ^ (row >> 2)) & 3);
        gload_lds16(A + (size_t)(bm+row)*LDK + k0 + sj*8, SA + cc*8);
    }
    {
        int cc = tid;                          // W: 512 chunks (128 rows x 4)
        int row = cc >> 2, jc = cc & 3;
        int sj = jc ^ ((row ^ (row >> 2)) & 3);
        gload_lds16(W + (size_t)(bn+row)*LDK + k0 + sj*8, SW + cc*8);
    }
}

__device__ __forceinline__ void kstep32(const __hip_bfloat16* CA, const __hip_bfloat16* CW,
    int wm, int wn, int r16, int physq, floatx4 (&acc)[4][4])
{
    bf16x8 af[4], wf[4];
#pragma unroll
    for (int i = 0; i < 4; ++i) {
        af[i] = *(const bf16x8*)(CA + (wm + i*16 + r16)*32 + physq*8);
        wf[i] = *(const bf16x8*)(CW + (wn + i*16 + r16)*32 + physq*8);
    }
#pragma unroll
    for (int mi = 0; mi < 4; ++mi)
#pragma unroll
        for (int ni = 0; ni < 4; ++ni)
            acc[mi][ni] = __builtin_amdgcn_mfma_f32_16x16x32_bf16(
                af[mi], wf[ni], acc[mi][ni], 0, 0, 0);
}

template<int LDK, int NSTEP>
__device__ __forceinline__ void gemm_loop(const __hip_bfloat16* __restrict__ A,
    const __hip_bfloat16* __restrict__ W,
    __hip_bfloat16* A0, __hip_bfloat16* W0, __hip_bfloat16* A1, __hip_bfloat16* W1,
    int bm, int bn, int tid, int wm, int wn, int r16, int physq,
    floatx4 (&acc)[4][4])
{
    stage32<LDK>(A, W, A0, W0, bm, bn, 0, tid);
    __syncthreads();
#pragma unroll 1
    for (int t = 0; t < NSTEP/2 - 1; ++t) {
        stage32<LDK>(A, W, A1, W1, bm, bn, (2*t+1)*32, tid);   // for step 2t+1
        kstep32(A0, W0, wm, wn, r16, physq, acc);              // step 2t
        __syncthreads();
        stage32<LDK>(A, W, A0, W0, bm, bn, (2*t+2)*32, tid);   // for step 2t+2
        kstep32(A1, W1, wm, wn, r16, physq, acc);              // step 2t+1
        __syncthreads();
    }
    stage32<LDK>(A, W, A1, W1, bm, bn, (NSTEP-1)*32, tid);
    kstep32(A0, W0, wm, wn, r16, physq, acc);                  // step NSTEP-2
    __syncthreads();
    kstep32(A1, W1, wm, wn, r16, physq, acc);                  // step NSTEP-1
    __syncthreads();
}

// ======== GEMM1: 256x128 tile, 8 waves; epilogue -> z16 / xbc16 / dtb ========
__global__ __launch_bounds__(512)
void gemm1_mfma(const __hip_bfloat16* __restrict__ A,   // fbf [ROWS][768]
                const __hip_bfloat16* __restrict__ W,   // wbf [3456][768]
                __hip_bfloat16* __restrict__ z16, __hip_bfloat16* __restrict__ xbc16,
                float* __restrict__ dtb, const float* __restrict__ dt_bias)
{
    __shared__ __align__(16) char smem[49152];
    __hip_bfloat16* A0 = (__hip_bfloat16*)smem;   // [256][32]
    __hip_bfloat16* A1 = A0 + 8192;
    __hip_bfloat16* W0 = A1 + 8192;               // [128][32]
    __hip_bfloat16* W1 = W0 + 4096;
    const int tid = threadIdx.x;
    const int lane = tid & 63, wave = tid >> 6;
    const int blk = blockIdx.x;
    const int m_tile = ((blk & 7) << 2) | ((blk >> 3) & 3);   // 32 M-tiles, XCD band
    const int bx = blk >> 5;                                   // N-tile 0..26
    const int bm = m_tile*256, bn = bx*128;
    const int wm = (wave & 3)*64, wn = (wave >> 2)*64;
    const int r16 = lane & 15, qbase = lane >> 4;
    const int physq = qbase ^ ((r16 ^ (r16 >> 2)) & 3);
    floatx4 acc[4][4] = {};
    gemm_loop<DMODEL, 24>(A, W, A0, W0, A1, W1, bm, bn, tid, wm, wn, r16, physq, acc);

    const int col = lane & 15, rowq = (lane >> 4)*4;
    if (bx == 26) {
        if (wn == 0) {
#pragma unroll
            for (int mi = 0; mi < 4; ++mi)
#pragma unroll
                for (int ni = 0; ni < 2; ++ni) {
                    int h = ni*16 + col;
                    if (h < NHEADS)
#pragma unroll
                        for (int r = 0; r < 4; ++r) {
                            int m = bm + wm + mi*16 + rowq + r;
                            dtb[(size_t)m*NHEADS + h] =
                                softplusf_(acc[mi][ni][r] + dt_bias[h]);
                        }
                }
        }
        return;
    }
    __hip_bfloat16* Tsm = (__hip_bfloat16*)smem;   // [128][LDE]
    __hip_bfloat16* dst; int ldd;
    if (bx < 12) { dst = z16 + bn;            ldd = DINNER; }
    else         { dst = xbc16 + bn - DINNER; ldd = DXBC;  }
    for (int half = 0; half < 2; ++half) {
        if (((wave & 3) >> 1) == half) {
#pragma unroll
            for (int mi = 0; mi < 4; ++mi)
#pragma unroll
                for (int ni = 0; ni < 4; ++ni)
#pragma unroll
                    for (int r = 0; r < 4; ++r)
                        Tsm[(wm - half*128 + mi*16 + rowq + r)*LDE + wn + ni*16 + col] =
                            __float2bfloat16(acc[mi][ni][r]);
        }
        __syncthreads();
#pragma unroll
        for (int it = 0; it < 4; ++it) {
            int e = it*512 + tid;
            int row = e >> 4, c0 = (e & 15)*8;
            bf16x8 v = *(const bf16x8*)(Tsm + row*LDE + c0);
            *(bf16x8*)(dst + (size_t)(bm + half*128 + row)*ldd + c0) = v;
        }
        __syncthreads();
    }
}

// ======== GEMM2: 256x128 tile; out = sig(gate)*rms_scale_r*(g @ Wn^T) + feature ====
__global__ __launch_bounds__(512)
void gemm2_mfma(const __hip_bfloat16* __restrict__ A,   // y16 [ROWS][1536] (gated)
                const __hip_bfloat16* __restrict__ W,   // owbf [768][1536]
                float* __restrict__ C,
                const float* __restrict__ gate, const float* __restrict__ resid,
                const float* __restrict__ rowsq)
{
    __shared__ __align__(16) char smem[49152];
    __shared__ float scale_lds[256];
    __hip_bfloat16* A0 = (__hip_bfloat16*)smem;   // [256][32]
    __hip_bfloat16* A1 = A0 + 8192;
    __hip_bfloat16* W0 = A1 + 8192;               // [128][32]
    __hip_bfloat16* W1 = W0 + 4096;
    const int tid = threadIdx.x;
    const int lane = tid & 63, wave = tid >> 6;
    const int blk = blockIdx.x;
    const int m_tile = ((blk & 7) << 2) | ((blk >> 3) & 3);
    const int bm = m_tile*256, bn = (blk >> 5)*128;     // n-tile 0..5
    const int wm = (wave & 3)*64, wn = (wave >> 2)*64;
    const int r16 = lane & 15, qbase = lane >> 4;
    const int physq = qbase ^ ((r16 ^ (r16 >> 2)) & 3);
    floatx4 acc[4][4] = {};
    gemm_loop<DINNER, 48>(A, W, A0, W0, A1, W1, bm, bn, tid, wm, wn, r16, physq, acc);

    if (tid < 256)
        scale_lds[tid] = rsqrtf(rowsq[bm + tid] * (1.f/DINNER) + 1e-5f);
    float gs = sigmoidf_(gate[0]);
    __syncthreads();
    const int col = lane & 15, rowq = (lane >> 4)*4;
    float* Tsm = (float*)smem;   // 64 x LDE2 fp32
    for (int qp = 0; qp < 4; ++qp) {
        if ((wave & 3) == qp) {
#pragma unroll
            for (int mi = 0; mi < 4; ++mi)
#pragma unroll
                for (int ni = 0; ni < 4; ++ni)
#pragma unroll
                    for (int r = 0; r < 4; ++r)
                        Tsm[(mi*16 + rowq + r)*LDE2 + wn + ni*16 + col] = acc[mi][ni][r];
        }
        __syncthreads();
#pragma unroll
        for (int it = 0; it < 4; ++it) {
            int e = it*512 + tid;
            int row = e >> 5, c0 = (e & 31)*4;
            float4 v = *(const float4*)(Tsm + row*LDE2 + c0);
            float sc = gs * scale_lds[qp*64 + row];
            size_t off = (size_t)(bm + qp*64 + row)*DMODEL + bn + c0;
            float4 rv = *(const float4*)(resid + off);
            v.x = sc*v.x + rv.x; v.y = sc*v.y + rv.y;
            v.z = sc*v.z + rv.z; v.w = sc*v.w + rv.w;
            *(float4*)(C + off) = v;
        }
        __syncthreads();
    }
}

// ---------------- fused fp32 -> bf16 casts, vectorized 8 elem/thread ----------------
#define NC1 (ROWS*DMODEL)
#define NC2 (NPAD1*DMODEL)
#define NC3 (DMODEL*DINNER)
#define NV1 (NC1/8)
#define NV2 (NC2/8)
#define NV3 (NC3/8)
__global__ __launch_bounds__(256)
void cast_all(const float* __restrict__ feature, const float* __restrict__ in_w,
              const float* __restrict__ out_w, const float* __restrict__ nw,
              __hip_bfloat16* __restrict__ fbf, __hip_bfloat16* __restrict__ wbf,
              __hip_bfloat16* __restrict__ owbf)
{
    int v = blockIdx.x*256 + threadIdx.x;
    if (v < NV1) {
        int i = v*8;
        float4 a = *(const float4*)(feature + i);
        float4 b = *(const float4*)(feature + i + 4);
        bf16x8 o;
        o[0]=cvt_bf(a.x); o[1]=cvt_bf(a.y); o[2]=cvt_bf(a.z); o[3]=cvt_bf(a.w);
        o[4]=cvt_bf(b.x); o[5]=cvt_bf(b.y); o[6]=cvt_bf(b.z); o[7]=cvt_bf(b.w);
        *(bf16x8*)(fbf + i) = o;
    } else if (v < NV1 + NV2) {
        int j = (v - NV1)*8;
        int n = j / DMODEL, k = j - n*DMODEL;
        bf16x8 o;
        if (n < DPROJ) {
            const float* s = in_w + (size_t)n*DMODEL + k;
            float4 a = *(const float4*)(s);
            float4 b = *(const float4*)(s + 4);
            o[0]=cvt_bf(a.x); o[1]=cvt_bf(a.y); o[2]=cvt_bf(a.z); o[3]=cvt_bf(a.w);
            o[4]=cvt_bf(b.x); o[5]=cvt_bf(b.y); o[6]=cvt_bf(b.z); o[7]=cvt_bf(b.w);
        } else {
#pragma unroll
            for (int q = 0; q < 8; ++q) o[q] = (__bf16)0.f;
        }
        *(bf16x8*)(wbf + j) = o;
    } else if (v < NV1 + NV2 + NV3) {
        int j = (v - NV1 - NV2)*8;
        int k = j % DINNER;
        float4 a  = *(const float4*)(out_w + j);
        float4 b  = *(const float4*)(out_w + j + 4);
        float4 na = *(const float4*)(nw + k);
        float4 nb = *(const float4*)(nw + k + 4);
        bf16x8 o;
        o[0]=cvt_bf(a.x*na.x); o[1]=cvt_bf(a.y*na.y); o[2]=cvt_bf(a.z*na.z); o[3]=cvt_bf(a.w*na.w);
        o[4]=cvt_bf(b.x*nb.x); o[5]=cvt_bf(b.y*nb.y); o[6]=cvt_bf(b.z*nb.z); o[7]=cvt_bf(b.w*nb.w);
        *(bf16x8*)(owbf + j) = o;
    }
}

// ======== conv4+SiLU, emits x_t/B_n/B_t/C_n in MFMA-ready layouts ========
__global__ __launch_bounds__(256)
void conv_k(const __hip_bfloat16* __restrict__ xbc16, const float* __restrict__ cw,
            const float* __restrict__ cbias,
            __hip_bfloat16* __restrict__ x_t,
            __hip_bfloat16* __restrict__ B_n, __hip_bfloat16* __restrict__ B_t,
            __hip_bfloat16* __restrict__ C_n)
{
    __shared__ __align__(16) __hip_bfloat16 in[131*LDTC];
    int ct = blockIdx.x, lt = blockIdx.y, b = blockIdx.z;
    int tid = threadIdx.x;
    int base = lt*128;
    for (int it = 0; it < 2096; it += 256) {
        int e = it + tid; if (e >= 2096) break;
        int row = e >> 4, c0 = (e & 15)*8;
        int l = base - 3 + row;
        bf16x8 v;
        if (l < 0) { for (int j = 0; j < 8; ++j) v[j] = (__bf16)0.f; }
        else v = *(const bf16x8*)(xbc16 + ((size_t)b*SEQ + l)*DXBC + ct*128 + c0);
        *(bf16x8*)(in + row*LDTC + c0) = v;
    }
    __syncthreads();
    int ch = tid & 127, lh = tid >> 7, l0 = lh*64;
    int g = ct*128 + ch;
    float w0 = cw[g*4+0], w1 = cw[g*4+1], w2 = cw[g*4+2], w3 = cw[g*4+3];
    float bias = cbias[g];
    float a0 = __bfloat162float(in[(l0+0)*LDTC + ch]);
    float a1 = __bfloat162float(in[(l0+1)*LDTC + ch]);
    float a2 = __bfloat162float(in[(l0+2)*LDTC + ch]);
    size_t trow = 0;
    if (ct < 12)      trow = ((size_t)b*NHEADS + (g>>6))*HEADDIM + (g & 63);
    else if (ct == 12) trow = (size_t)b*DSTATE + ch;
    bf16x8 obuf;
#pragma unroll
    for (int li = 0; li < 64; ++li) {
        float a3 = __bfloat162float(in[(l0+li+3)*LDTC + ch]);
        float o = siluf_(bias + w0*a0 + w1*a1 + w2*a2 + w3*a3);
        a0 = a1; a1 = a2; a2 = a3;
        __hip_bfloat16 ob = __float2bfloat16(o);
        size_t rr = (size_t)b*SEQ + base + l0 + li;
        if (ct == 12)      B_n[rr*DSTATE + ch] = ob;
        else if (ct == 13) C_n[rr*DSTATE + ch] = ob;
        obuf[li & 7] = *(const __bf16*)&ob;
        if ((li & 7) == 7 && ct <= 12) {
            __hip_bfloat16* dst = (ct < 12) ? x_t : B_t;
            *(bf16x8*)(dst + trow*SEQ + base + l0 + (li - 7)) = obuf;
        }
    }
}

// ---------------- intra-chunk inclusive cumsum of dt*A ----------------
__global__ __launch_bounds__(128)
void scan_k(const float* __restrict__ dtb, const float* __restrict__ A_log,
            float* __restrict__ acum)
{
    int c = blockIdx.x & 31;
    int h = (blockIdx.x >> 5) % NHEADS;
    int b = blockIdx.x / (32*NHEADS);
    int l = threadIdx.x;
    float A = -expf(A_log[h]);
    size_t row = (size_t)b*SEQ + c*CHUNK + l;
    float v = dtb[row*NHEADS + h] * A;
    __shared__ float sh[128];
    sh[l] = v; __syncthreads();
    for (int off=1; off<128; off<<=1){
        float t = (l>=off) ? sh[l-off] : 0.f;
        __syncthreads();
        sh[l] += t;
        __syncthreads();
    }
    acum[((b*NHEADS+h)*NCHUNK + c)*CHUNK + l] = sh[l];
}

// ======== CB[l][s] = sum_n C[l][n]*B[s][n], per (b,c), LDS-free, tril tiles only ========
__global__ __launch_bounds__(256)
void cb_mfma(const __hip_bfloat16* __restrict__ B_n, const __hip_bfloat16* __restrict__ C_n,
             __hip_bfloat16* __restrict__ CB16)
{
    int c = blockIdx.x & 31, b = blockIdx.x >> 5;
    size_t base = (size_t)b*SEQ + c*CHUNK;
    int tid = threadIdx.x, lane = tid & 63, wave = tid >> 6;
    int r16 = lane & 15, kq = (lane>>4)*8;
    floatx4 acc[2][8] = {};
#pragma unroll
    for (int ks = 0; ks < 4; ++ks) {
        int k0 = ks*32 + kq;
        bf16x8 af[2], bfv[8];
#pragma unroll
        for (int mt = 0; mt < 2; ++mt)
            af[mt] = *(const bf16x8*)(C_n + (base + (wave*2+mt)*16 + r16)*DSTATE + k0);
#pragma unroll
        for (int st = 0; st < 8; ++st)
            bfv[st] = *(const bf16x8*)(B_n + (base + st*16 + r16)*DSTATE + k0);
#pragma unroll
        for (int mt = 0; mt < 2; ++mt)
#pragma unroll
            for (int st = 0; st < 8; ++st)
                if (st <= wave*2+mt)
                    acc[mt][st] = __builtin_amdgcn_mfma_f32_16x16x32_bf16(
                        af[mt], bfv[st], acc[mt][st], 0,0,0);
    }
    size_t cbb = (size_t)(b*NCHUNK+c)*CHUNK*CHUNK;
    int scol = lane & 15, rowq = (lane>>4)*4;
#pragma unroll
    for (int mt = 0; mt < 2; ++mt)
#pragma unroll
        for (int st = 0; st < 8; ++st)
            if (st <= wave*2+mt)
#pragma unroll
                for (int r = 0; r < 4; ++r)
                    CB16[cbb + (size_t)((wave*2+mt)*16 + rowq + r)*CHUNK + st*16 + scol] =
                        __float2bfloat16(acc[mt][st][r]);
}

// ======== states[p][n] = sum_l (x[l,p]*f[l]) * B[l,n], f = dt*dec ========
__global__ __launch_bounds__(256)
void states_mfma(const __hip_bfloat16* __restrict__ x_t, const __hip_bfloat16* __restrict__ B_t,
                 const float* __restrict__ dtb, const float* __restrict__ acum,
                 __hip_bfloat16* __restrict__ states)
{
    __shared__ float f[128];
    int c = blockIdx.x & 31;
    int h = (blockIdx.x>>5) % NHEADS;
    int b = blockIdx.x/(32*NHEADS);
    int tid = threadIdx.x, lane = tid & 63, wave = tid >> 6;
    int arow = ((b*NHEADS+h)*NCHUNK + c)*CHUNK;
    size_t rbase = (size_t)b*SEQ + c*CHUNK;
    if (tid < 128) {
        float alast = acum[arow + 127];
        f[tid] = dtb[(rbase + tid)*NHEADS + h] * expf(alast - acum[arow + tid]);
    }
    __syncthreads();
    int r16 = lane & 15, kq = (lane>>4)*8;
    size_t xtb = ((size_t)b*NHEADS + h)*HEADDIM;
    int cl = c*CHUNK;
    floatx4 acc[8] = {};
#pragma unroll
    for (int ks = 0; ks < 4; ++ks) {
        int k0 = ks*32 + kq;
        bf16x8 xa = *(const bf16x8*)(x_t + (xtb + wave*16 + r16)*SEQ + cl + k0);
        bf16x8 af;
#pragma unroll
        for (int j = 0; j < 8; ++j)
            af[j] = (__bf16)((float)xa[j] * f[k0 + j]);
        bf16x8 bfv[8];
#pragma unroll
        for (int nt = 0; nt < 8; ++nt)
            bfv[nt] = *(const bf16x8*)(B_t + ((size_t)b*DSTATE + nt*16 + r16)*SEQ + cl + k0);
#pragma unroll
        for (int nt = 0; nt < 8; ++nt)
            acc[nt] = __builtin_amdgcn_mfma_f32_16x16x32_bf16(af, bfv[nt], acc[nt], 0,0,0);
    }
    size_t sb = ((size_t)(b*NCHUNK+c)*NHEADS + h)*(HEADDIM*DSTATE);
    int ncol = lane & 15, rowq = (lane>>4)*4;
#pragma unroll
    for (int nt = 0; nt < 8; ++nt)
#pragma unroll
        for (int r = 0; r < 4; ++r)
            states[sb + (size_t)(wave*16 + rowq + r)*DSTATE + nt*16 + ncol] =
                __float2bfloat16(acc[nt][r]);
}

// ---- sequential inter-chunk recurrence, in place (bf16): states[c] := prev[c] ----
__global__ __launch_bounds__(256)
void recur_k(__hip_bfloat16* __restrict__ states, const float* __restrict__ acum)
{
    int pb = blockIdx.x & 3;
    int bh = blockIdx.x >> 2;
    int h = bh % NHEADS, b = bh / NHEADS;
    int voff = (pb*256 + threadIdx.x)*8;
    const size_t cstride = (size_t)NHEADS*HEADDIM*DSTATE;
    size_t base0 = ((size_t)(b*NCHUNK)*NHEADS + h)*(HEADDIM*DSTATE) + voff;
    bf16x8 st[NCHUNK];
    float ev[NCHUNK];
#pragma unroll
    for (int c = 0; c < NCHUNK; ++c)
        st[c] = *(const bf16x8*)(states + base0 + (size_t)c*cstride);
#pragma unroll
    for (int c = 0; c < NCHUNK; ++c)
        ev[c] = expf(acum[((b*NHEADS+h)*NCHUNK + c)*CHUNK + 127]);
    float S[8] = {};
#pragma unroll
    for (int c = 0; c < NCHUNK; ++c) {
        bf16x8 pv;
#pragma unroll
        for (int j = 0; j < 8; ++j) {
            pv[j] = (__bf16)S[j];
            S[j] = S[j]*ev[c] + (float)st[c][j];
        }
        *(bf16x8*)(states + base0 + (size_t)c*cstride) = pv;
    }
}

// ======== Y = [tril(CB*exp(dAc)*dt)+D*I] @ x + (C*exp(ac)) @ prev^T; then
//          g = Y*silu(z) -> y16; rowsq += per-row sum(g^2) (atomic) ========
__global__ __launch_bounds__(512)
void y_mfma(const __hip_bfloat16* __restrict__ x_t, const __hip_bfloat16* __restrict__ z16,
            const __hip_bfloat16* __restrict__ C_n, const __hip_bfloat16* __restrict__ CB16,
            const __hip_bfloat16* __restrict__ states, const float* __restrict__ dtb,
            const float* __restrict__ acum, const float* __restrict__ Dp,
            __hip_bfloat16* __restrict__ y16, float* __restrict__ rowsq)
{
    __shared__ float ac[128], dts[128];
    int c = blockIdx.x & 31;
    int h = (blockIdx.x>>5) % NHEADS;
    int b = blockIdx.x/(32*NHEADS);
    int tid = threadIdx.x, lane = tid & 63, wave = tid >> 6;
    int arow = ((b*NHEADS+h)*NCHUNK + c)*CHUNK;
    size_t rbase = (size_t)b*SEQ + c*CHUNK;
    if (tid < 128) {
        ac[tid]  = acum[arow + tid];
        dts[tid] = dtb[(rbase + tid)*NHEADS + h];
    }
    __syncthreads();
    int r16 = lane & 15, kq = (lane>>4)*8;
    int l = wave*16 + r16;
    float acl = ac[l];
    float Dh = Dp[h];
    size_t cbb = (size_t)(b*NCHUNK+c)*CHUNK*CHUNK;
    size_t xtb = ((size_t)b*NHEADS + h)*HEADDIM;
    int cl = c*CHUNK;
    floatx4 acc[4] = {};
    int nks = ((wave+1)*16 + 31) >> 5;
    for (int ks = 0; ks < nks; ++ks) {
        int k0 = ks*32 + kq;
        bf16x8 cbv = *(const bf16x8*)(CB16 + cbb + (size_t)l*CHUNK + k0);
        bf16x8 af;
#pragma unroll
        for (int j = 0; j < 8; ++j) {
            int s = k0 + j;
            float w = (s <= l) ? (float)cbv[j] * expf(acl - ac[s]) * dts[s] : 0.f;
            if (s == l) w += Dh;               // D*x folded into the diagonal
            af[j] = (__bf16)w;
        }
        bf16x8 bfv[4];
#pragma unroll
        for (int pt = 0; pt < 4; ++pt)
            bfv[pt] = *(const bf16x8*)(x_t + (xtb + pt*16 + r16)*SEQ + cl + k0);
#pragma unroll
        for (int pt = 0; pt < 4; ++pt)
            acc[pt] = __builtin_amdgcn_mfma_f32_16x16x32_bf16(af, bfv[pt], acc[pt], 0,0,0);
    }
    float eal = expf(acl);
    size_t sb = ((size_t)(b*NCHUNK+c)*NHEADS + h)*(HEADDIM*DSTATE);
#pragma unroll
    for (int ks = 0; ks < 4; ++ks) {
        int k0 = ks*32 + kq;
        bf16x8 cv = *(const bf16x8*)(C_n + (rbase + l)*DSTATE + k0);
        bf16x8 af;
#pragma unroll
        for (int j = 0; j < 8; ++j)
            af[j] = (__bf16)((float)cv[j] * eal);
        bf16x8 bfv[4];
#pragma unroll
        for (int pt = 0; pt < 4; ++pt)
            bfv[pt] = *(const bf16x8*)(states + sb + (size_t)(pt*16 + r16)*DSTATE + k0);
#pragma unroll
        for (int pt = 0; pt < 4; ++pt)
            acc[pt] = __builtin_amdgcn_mfma_f32_16x16x32_bf16(af, bfv[pt], acc[pt], 0,0,0);
    }
    // epilogue: g = acc * silu(z); store; per-row sumsq via shuffle + atomic
    int pcol = lane & 15, rowq = (lane>>4)*4;
    float sr[4] = {0.f, 0.f, 0.f, 0.f};
#pragma unroll
    for (int pt = 0; pt < 4; ++pt)
#pragma unroll
        for (int r = 0; r < 4; ++r) {
            int ll = wave*16 + rowq + r;
            int p = pt*16 + pcol;
            size_t rr = rbase + ll;
            float zv = __bfloat162float(z16[rr*DINNER + h*HEADDIM + p]);
            float g = acc[pt][r] * siluf_(zv);
            y16[rr*DINNER + h*HEADDIM + p] = __float2bfloat16(g);
            sr[r] += g*g;
        }
#pragma unroll
    for (int r = 0; r < 4; ++r) {
        float s = sr[r];
        s += __shfl_xor(s, 1); s += __shfl_xor(s, 2);
        s += __shfl_xor(s, 4); s += __shfl_xor(s, 8);
        if (pcol == 0)
            atomicAdd(rowsq + rbase + wave*16 + rowq + r, s);
    }
}

extern "C" void kernel_launch(void* const* d_in, const int* in_sizes, int n_in,
                              void* d_out, int out_size, void* d_ws, size_t ws_size,
                              hipStream_t stream)
{
    const float* feature = (const float*)d_in[0];
    const float* gate1   = (const float*)d_in[1];
    const float* in_w    = (const float*)d_in[2];
    const float* conv_w  = (const float*)d_in[3];
    const float* conv_b  = (const float*)d_in[4];
    const float* dt_bias = (const float*)d_in[5];
    const float* A_log   = (const float*)d_in[6];
    const float* Dp      = (const float*)d_in[7];
    const float* norm_w  = (const float*)d_in[8];
    const float* out_w   = (const float*)d_in[9];
    float* out = (float*)d_out;

    // workspace layout — ~161 MB (< 256 MiB)
    char* p = (char*)d_ws;
    __hip_bfloat16* z16   = (__hip_bfloat16*)p; p += (size_t)ROWS*DINNER*2;  // 25.2 MB
    __hip_bfloat16* xbc16 = (__hip_bfloat16*)p; p += (size_t)ROWS*DXBC*2;    // 29.4 MB
    __hip_bfloat16* x_t   = (__hip_bfloat16*)p; p += (size_t)ROWS*DINNER*2;  // 25.2 MB
    __hip_bfloat16* B_n   = (__hip_bfloat16*)p; p += (size_t)ROWS*DSTATE*2;  // 2.1 MB
    __hip_bfloat16* B_t   = (__hip_bfloat16*)p; p += (size_t)ROWS*DSTATE*2;  // 2.1 MB
    __hip_bfloat16* C_n   = (__hip_bfloat16*)p; p += (size_t)ROWS*DSTATE*2;  // 2.1 MB
    float* dtb    = (float*)p;            p += (size_t)ROWS*NHEADS*4;        // 0.8 MB
    float* acum   = (float*)p;            p += (size_t)B_SZ*NHEADS*NCHUNK*CHUNK*4; // 0.8 MB
    float* rowsq  = (float*)p;            p += (size_t)ROWS*4;               // 32 KB
    __hip_bfloat16* CB16 = (__hip_bfloat16*)p; p += (size_t)B_SZ*NCHUNK*CHUNK*CHUNK*2; // 2.1 MB
    __hip_bfloat16* states = (__hip_bfloat16*)p; p += (size_t)B_SZ*NCHUNK*NHEADS*HEADDIM*DSTATE*2; // 25.2 MB
    __hip_bfloat16* y16  = (__hip_bfloat16*)p; p += (size_t)ROWS*DINNER*2;   // 25.2 MB
    __hip_bfloat16* fbf  = (__hip_bfloat16*)p; p += (size_t)ROWS*DMODEL*2;   // 12.6 MB
    __hip_bfloat16* wbf  = (__hip_bfloat16*)p; p += (size_t)NPAD1*DMODEL*2;  //  5.3 MB
    __hip_bfloat16* owbf = (__hip_bfloat16*)p; p += (size_t)DMODEL*DINNER*2; //  2.4 MB

    cast_all<<<(NV1+NV2+NV3+255)/256, 256, 0, stream>>>(feature, in_w, out_w, norm_w,
                                                        fbf, wbf, owbf);
    hipMemsetAsync(rowsq, 0, (size_t)ROWS*4, stream);

    gemm1_mfma<<<27*32, 512, 0, stream>>>(fbf, wbf, z16, xbc16, dtb, dt_bias);
    conv_k<<<dim3(14, 32, B_SZ), 256, 0, stream>>>(xbc16, conv_w, conv_b,
                                                   x_t, B_n, B_t, C_n);
    scan_k<<<B_SZ*NHEADS*NCHUNK, 128, 0, stream>>>(dtb, A_log, acum);
    cb_mfma<<<B_SZ*NCHUNK, 256, 0, stream>>>(B_n, C_n, CB16);
    states_mfma<<<B_SZ*NHEADS*NCHUNK, 256, 0, stream>>>(x_t, B_t, dtb, acum, states);
    recur_k<<<B_SZ*NHEADS*4, 256, 0, stream>>>(states, acum);
    y_mfma<<<B_SZ*NHEADS*NCHUNK, 512, 0, stream>>>(x_t, z16, C_n, CB16, states,
                                                   dtb, acum, Dp, y16, rowsq);
    gemm2_mfma<<<6*32, 512, 0, stream>>>(y16, owbf, out, gate1, feature, rowsq);
}